// Round 8
// baseline (197.435 us; speedup 1.0000x reference)
//
#include <hip/hip_runtime.h>

// B=2, S=2048, E=1024, H=16, D=64
#define SEQ 2048
#define EMB 1024
#define KDIM 1024
#define CF 0.180336880111113f  // (1/sqrt(64)) * log2(e), folded into Q

typedef __attribute__((ext_vector_type(8))) short short8_t;
typedef __attribute__((ext_vector_type(4))) float floatx4;
typedef __attribute__((ext_vector_type(4))) unsigned short ushort4_t;

#define GLOAD16(gp, lp)                                                        \
  __builtin_amdgcn_global_load_lds(                                            \
      (const __attribute__((address_space(1))) void*)(gp),                     \
      (__attribute__((address_space(3))) void*)(lp), 16, 0, 0)

#define WGBAR()                                   \
  do {                                            \
    __asm__ __volatile__("" ::: "memory");        \
    __builtin_amdgcn_s_barrier();                 \
    __asm__ __volatile__("" ::: "memory");        \
  } while (0)

static __device__ __forceinline__ unsigned short f2bf(float x) {
  unsigned int u = __float_as_uint(x);
  return (unsigned short)((u + 0x7fffu + ((u >> 16) & 1u)) >> 16);
}

// ---------------------------------------------------------------------------
// Fused prepass: blockIdx 0..4095   -> hs fp32 -> bf16
//                4096..4863         -> c_attn_w [1024,3072] -> w1t [3072,1024]
//                4864..5119         -> c_proj_w [1024,1024] -> w2t [1024,1024]
// ---------------------------------------------------------------------------
static __device__ __forceinline__ void tconv_tile(
    const float* __restrict__ W, unsigned short* __restrict__ T, int N, int K,
    int n0, int k0, int tid) {
  __shared__ float Tl[64][65];
  const int lx = tid & 15, ly = tid >> 4;
#pragma unroll
  for (int u = 0; u < 4; ++u) {
    int r = u * 16 + ly;
    float4 v = *(const float4*)&W[(size_t)(k0 + r) * N + n0 + lx * 4];
    Tl[r][lx * 4 + 0] = v.x;
    Tl[r][lx * 4 + 1] = v.y;
    Tl[r][lx * 4 + 2] = v.z;
    Tl[r][lx * 4 + 3] = v.w;
  }
  __syncthreads();
#pragma unroll
  for (int u = 0; u < 4; ++u) {
    int n = u * 16 + ly;
    ushort4_t h;
#pragma unroll
    for (int v = 0; v < 4; ++v) h[v] = f2bf(Tl[lx * 4 + v][n]);
    *(ushort4_t*)&T[(size_t)(n0 + n) * K + k0 + lx * 4] = h;
  }
}

__global__ __launch_bounds__(256) void prep(
    const float* __restrict__ hs, const float* __restrict__ caw,
    const float* __restrict__ cpw, unsigned short* __restrict__ hsb,
    unsigned short* __restrict__ w1t, unsigned short* __restrict__ w2t) {
  const int bid = blockIdx.x, tid = threadIdx.x;
  if (bid < 4096) {
    const int i = bid * 256 + tid;
    float4 v = *(const float4*)&hs[(size_t)i * 4];
    ushort4_t h = {f2bf(v.x), f2bf(v.y), f2bf(v.z), f2bf(v.w)};
    *(ushort4_t*)&hsb[(size_t)i * 4] = h;
  } else if (bid < 4864) {
    const int idx = bid - 4096;
    tconv_tile(caw, w1t, 3 * EMB, EMB, (idx % 48) * 64, (idx / 48) * 64, tid);
  } else {
    const int idx = bid - 4864;
    tconv_tile(cpw, w2t, EMB, EMB, (idx % 16) * 64, (idx / 16) * 64, tid);
  }
}

// ---------------------------------------------------------------------------
// Plain bf16 MFMA GEMM, BK=64, transposed-C accumulators (regs = 4
// consecutive output cols):  C = A @ Bt^T + bias.  Tile 128 x BN.
//   A: [M,1024] bf16 row-major;  Bt: [N,1024] bf16 (W transposed)
// MODE 0 (BN=128, grid 24x32): cols<2048 -> qk bf16 [B,S,2048] (q scaled CF,
//   ushort4 stores); cols>=2048 -> vt bf16 [B,H,D,S] (4 row-strided stores).
// MODE 2 (BN=64, grid 16x32): fp32 out [M,1024], float4 stores.
// ---------------------------------------------------------------------------
template <int MODE, int BN>
__global__ __launch_bounds__(256) void gemm_bf(
    const unsigned short* __restrict__ Ag, const unsigned short* __restrict__ Bg,
    const float* __restrict__ bias, float* __restrict__ outF,
    unsigned short* __restrict__ qk, unsigned short* __restrict__ vt) {
  __shared__ __attribute__((aligned(16))) unsigned short Ah[128 * 64];
  __shared__ __attribute__((aligned(16))) unsigned short Bh[BN * 64];
  const int NJ = BN / 32;  // j-frag groups per wave

  const int tid = threadIdx.x;
  const int w = tid >> 6, lane = tid & 63;
  const int quad = lane >> 4, c = lane & 15;
  const int bm = blockIdx.y * 128, bn = blockIdx.x * BN;
  const int wm = (w >> 1) * 64, wn = (w & 1) * (BN / 2);

  // staging: waves 0,1 -> A halves; waves 2,3 -> B halves
  const unsigned short* gsrc = (w < 2) ? Ag : Bg;
  unsigned short* ldst = (w < 2) ? (Ah + (w & 1) * 64 * 64) : (Bh + (w & 1) * (BN / 2) * 64);
  const int rbase = (w < 2) ? (bm + (w & 1) * 64) : (bn + (w & 1) * (BN / 2));
  const int nloads = (w < 2) ? 8 : (BN / 16);
  const int srow = lane >> 3;          // 0..7
  const int sblk = (lane & 7) ^ srow;  // XOR chunk swizzle (8x16B chunks/row)
  const char* gp0 = (const char*)(gsrc + (size_t)(rbase + srow) * KDIM) + sblk * 16;

  floatx4 acc[4][NJ];
  const floatx4 z = {0.f, 0.f, 0.f, 0.f};
#pragma unroll
  for (int i = 0; i < 4; ++i)
#pragma unroll
    for (int j = 0; j < NJ; ++j) acc[i][j] = z;

  const int rk = c & 7;  // read-side swizzle key (row&7 == c&7)

  for (int k0 = 0; k0 < KDIM; k0 += 64) {
    __syncthreads();
    const char* gp = gp0 + k0 * 2;
    for (int i = 0; i < nloads; ++i) GLOAD16(gp + (size_t)i * 8 * (KDIM * 2), &ldst[i * 512]);
    __syncthreads();

#pragma unroll
    for (int kq = 0; kq < 2; ++kq) {
      const int oct = ((4 * kq + quad) ^ rk) * 8;
      short8_t a[4], b[NJ];
#pragma unroll
      for (int i = 0; i < 4; ++i)
        a[i] = *(const short8_t*)&Ah[(wm + 16 * i + c) * 64 + oct];
#pragma unroll
      for (int j = 0; j < NJ; ++j)
        b[j] = *(const short8_t*)&Bh[(wn + 16 * j + c) * 64 + oct];
      // transposed: lane = A-row (m), regs = 4 consecutive B-rows (n)
#pragma unroll
      for (int i = 0; i < 4; ++i)
#pragma unroll
        for (int j = 0; j < NJ; ++j)
          acc[i][j] = __builtin_amdgcn_mfma_f32_16x16x32_bf16(b[j], a[i], acc[i][j], 0, 0, 0);
    }
  }

#pragma unroll
  for (int i = 0; i < 4; ++i) {
    const int row = bm + wm + 16 * i + c;
#pragma unroll
    for (int j = 0; j < NJ; ++j) {
      const int col0 = bn + wn + 16 * j + quad * 4;
      floatx4 v = acc[i][j] + *(const floatx4*)&bias[col0];
      if (MODE == 0) {
        if (col0 < 1024) v = v * CF;
        if (col0 < 2048) {
          ushort4_t pk = {f2bf(v[0]), f2bf(v[1]), f2bf(v[2]), f2bf(v[3])};
          *(ushort4_t*)&qk[(size_t)row * 2048 + col0] = pk;
        } else {
          const int c2 = col0 - 2048, hh = c2 >> 6, d0 = c2 & 63;
          const int bb = row >> 11, s = row & 2047;
          unsigned short* vb = &vt[((size_t)(bb * 16 + hh) * 64 + d0) * 2048 + s];
          vb[0 * 2048] = f2bf(v[0]);
          vb[1 * 2048] = f2bf(v[1]);
          vb[2 * 2048] = f2bf(v[2]);
          vb[3 * 2048] = f2bf(v[3]);
        }
      } else {
        *(floatx4*)&outF[(size_t)row * 1024 + col0] = v;
      }
    }
  }
}

// ---------------------------------------------------------------------------
// K/V staging: waves 0,1 stage K rows w*32..+31; waves 2,3 stage V^T rows.
// 4 GLOAD16 per wave per tile.
// ---------------------------------------------------------------------------
static __device__ __forceinline__ void stage_kv(
    int w, int srow, int sblkg, const unsigned short* __restrict__ gK,
    const unsigned short* __restrict__ gV, unsigned short* Kbuf,
    unsigned short* Vbuf, int jt) {
  if (w < 2) {
    const unsigned short* g0 = gK + (size_t)(jt * 64 + w * 32 + srow) * 2048 + sblkg * 8;
    unsigned short* l0 = &Kbuf[(w * 32) * 64];
#pragma unroll
    for (int i = 0; i < 4; ++i) GLOAD16(g0 + (size_t)i * 8 * 2048, &l0[i * 512]);
  } else {
    const unsigned short* g0 = gV + (size_t)((w - 2) * 32 + srow) * 2048 + jt * 64 + sblkg * 8;
    unsigned short* l0 = &Vbuf[((w - 2) * 32) * 64];
#pragma unroll
    for (int i = 0; i < 4; ++i) GLOAD16(g0 + (size_t)i * 8 * 2048, &l0[i * 512]);
  }
}

// ---------------------------------------------------------------------------
// bf16 MFMA flash attention, fixed-max softmax, S^T formulation.
// 64 q-rows PER WAVE (mi=0..3): K/V fragment reads amortize over 2x rows
// vs R7 -> per-CU LDS traffic -33% (the measured wall). Double-buffered K/V,
// single barrier per tile, depth-1 DMA prefetch.
// Grid (S/256, H, B) = (8,16,2), 256 thr. Wave w owns q-rows q0+64w..+63.
// LDS: 2x8K (K) + 2x8K (V) + 32K (P) = 64 KB.
// ---------------------------------------------------------------------------
__global__ __launch_bounds__(256) void attn7(
    const unsigned short* __restrict__ qk, const unsigned short* __restrict__ vt,
    unsigned short* __restrict__ ao) {
  __shared__ __attribute__((aligned(16))) unsigned short Ks[2][64 * 64];  // 16 KB
  __shared__ __attribute__((aligned(16))) unsigned short Vs[2][64 * 64];  // 16 KB
  __shared__ __attribute__((aligned(16))) unsigned short Ps[4][64 * 64];  // 32 KB

  const int tid = threadIdx.x;
  const int w = tid >> 6, lane = tid & 63, quad = lane >> 4, c = lane & 15;
  const int q0 = blockIdx.x * 256, h = blockIdx.y, b = blockIdx.z;
  const int rk = c & 7;

  // persistent Q frags (B-operand): 4 mi-groups x 2 d-steps; q pre-scaled CF
  short8_t qf[4][2];
  {
    const size_t rb = (size_t)b * SEQ + q0 + w * 64;
#pragma unroll
    for (int mi = 0; mi < 4; ++mi) {
      const size_t qr = (rb + mi * 16 + c) * 2048 + h * 64 + quad * 8;
      qf[mi][0] = *(const short8_t*)&qk[qr];
      qf[mi][1] = *(const short8_t*)&qk[qr + 32];
    }
  }
  __asm__ __volatile__("s_waitcnt vmcnt(0)" ::: "memory");  // clean vmcnt queue

  floatx4 O[4][4], Osum[4];
  const floatx4 z = {0.f, 0.f, 0.f, 0.f};
#pragma unroll
  for (int mi = 0; mi < 4; ++mi) {
    Osum[mi] = z;
#pragma unroll
    for (int dg = 0; dg < 4; ++dg) O[mi][dg] = z;
  }
  short8_t ones;
#pragma unroll
  for (int e = 0; e < 8; ++e) ones[e] = (short)0x3F80;  // bf16 1.0

  const int srow = lane >> 3;           // 0..7
  const int sblkg = (lane & 7) ^ srow;  // staging chunk swizzle
  const unsigned short* gK = qk + (size_t)b * SEQ * 2048 + 1024 + h * 64;
  const unsigned short* gV = vt + (size_t)(b * 16 + h) * 64 * 2048;
  unsigned short* myPs = Ps[w];

  stage_kv(w, srow, sblkg, gK, gV, Ks[0], Vs[0], 0);

  for (int t = 0; t < 32; ++t) {
    // own stage-t loads landed (vmcnt is per-wave; only own 4 in flight)
    __asm__ __volatile__("s_waitcnt vmcnt(0)" ::: "memory");
    WGBAR();  // all waves: stage-t landed AND compute t-1 finished
    // prefetch t+1 into the buffer compute(t-1) just vacated
    stage_kv(w, srow, sblkg, gK, gV, Ks[(t + 1) & 1], Vs[(t + 1) & 1], (t + 1) & 31);
    const unsigned short* Kc = Ks[t & 1];
    const unsigned short* Vc = Vs[t & 1];

    // S^T = K Q^T: lane = q, regs = j (consecutive within quad)
    floatx4 S[4][4];
#pragma unroll
    for (int mi = 0; mi < 4; ++mi)
#pragma unroll
      for (int jg = 0; jg < 4; ++jg) S[mi][jg] = z;
#pragma unroll
    for (int kd = 0; kd < 2; ++kd) {
      const int oct = ((4 * kd + quad) ^ rk) * 8;
#pragma unroll
      for (int jg = 0; jg < 4; ++jg) {
        short8_t kf = *(const short8_t*)&Kc[(jg * 16 + c) * 64 + oct];
#pragma unroll
        for (int mi = 0; mi < 4; ++mi)
          S[mi][jg] = __builtin_amdgcn_mfma_f32_16x16x32_bf16(kf, qf[mi][kd], S[mi][jg], 0, 0, 0);
      }
    }

    // P = exp2(S^T), truncate to bf16, pack consecutive-j pairs -> b32 LDS
#pragma unroll
    for (int mi = 0; mi < 4; ++mi) {
      const int qrow = (mi * 16 + c) * 64;
#pragma unroll
      for (int jg = 0; jg < 4; ++jg) {
        float p0 = __builtin_amdgcn_exp2f(S[mi][jg][0]);
        float p1 = __builtin_amdgcn_exp2f(S[mi][jg][1]);
        float p2 = __builtin_amdgcn_exp2f(S[mi][jg][2]);
        float p3 = __builtin_amdgcn_exp2f(S[mi][jg][3]);
        unsigned int pk01 = (__float_as_uint(p1) & 0xFFFF0000u) | (__float_as_uint(p0) >> 16);
        unsigned int pk23 = (__float_as_uint(p3) & 0xFFFF0000u) | (__float_as_uint(p2) >> 16);
        const int jp0 = 8 * jg + 2 * quad;
#pragma unroll
        for (int u = 0; u < 2; ++u) {
          const int jp = jp0 + u;
          const int off = ((jp >> 2) ^ rk) * 8 + (jp & 3) * 2;
          *(unsigned int*)&myPs[qrow + off] = u ? pk23 : pk01;
        }
      }
    }
    __asm__ __volatile__("s_waitcnt lgkmcnt(0)" ::: "memory");

    // PV: O^T += V^T P^T ; l += ones . P^T
#pragma unroll
    for (int kq = 0; kq < 2; ++kq) {
      const int oct = ((4 * kq + quad) ^ rk) * 8;
      short8_t pb[4];
#pragma unroll
      for (int mi = 0; mi < 4; ++mi) {
        pb[mi] = *(const short8_t*)&myPs[(mi * 16 + c) * 64 + oct];
        Osum[mi] = __builtin_amdgcn_mfma_f32_16x16x32_bf16(ones, pb[mi], Osum[mi], 0, 0, 0);
      }
#pragma unroll
      for (int dg = 0; dg < 4; ++dg) {
        short8_t vf = *(const short8_t*)&Vc[(dg * 16 + c) * 64 + oct];
#pragma unroll
        for (int mi = 0; mi < 4; ++mi)
          O[mi][dg] = __builtin_amdgcn_mfma_f32_16x16x32_bf16(vf, pb[mi], O[mi][dg], 0, 0, 0);
      }
    }
  }

  __asm__ __volatile__("s_waitcnt vmcnt(0)" ::: "memory");  // drain trailing DMA

  // epilogue: lane = q, regs = consecutive d -> packed ushort4 stores
#pragma unroll
  for (int mi = 0; mi < 4; ++mi) {
    const float inv = 1.0f / Osum[mi][0];
    const size_t row = (size_t)b * SEQ + q0 + w * 64 + mi * 16 + c;
#pragma unroll
    for (int dg = 0; dg < 4; ++dg) {
      ushort4_t ov = {f2bf(O[mi][dg][0] * inv), f2bf(O[mi][dg][1] * inv),
                      f2bf(O[mi][dg][2] * inv), f2bf(O[mi][dg][3] * inv)};
      *(ushort4_t*)&ao[row * EMB + h * 64 + dg * 16 + quad * 4] = ov;
    }
  }
}

// ---------------------------------------------------------------------------
extern "C" void kernel_launch(void* const* d_in, const int* in_sizes, int n_in,
                              void* d_out, int out_size, void* d_ws, size_t ws_size,
                              hipStream_t stream) {
  const float* hs = (const float*)d_in[0];        // [B,S,E]
  const float* c_attn_w = (const float*)d_in[1];  // [E,3E]
  const float* c_attn_b = (const float*)d_in[2];  // [3E]
  const float* c_proj_w = (const float*)d_in[3];  // [E,E]
  const float* c_proj_b = (const float*)d_in[4];  // [E]
  float* out = (float*)d_out;                     // [B,S,E] fp32

  char* ws = (char*)d_ws;
  unsigned short* hsb = (unsigned short*)(ws + 0);         // 8.39 MB [B,S,E] bf16
  unsigned short* qk  = (unsigned short*)(ws + 8388608);   // 16.8 MB [B,S,2048]
  unsigned short* vt  = (unsigned short*)(ws + 25165824);  // 8.39 MB [B,H,D,S]
  unsigned short* aob = (unsigned short*)(ws + 33554432);  // 8.39 MB [B,S,E] bf16
  unsigned short* w1t = (unsigned short*)(ws + 41943040);  // 6.29 MB [3072,1024]
  unsigned short* w2t = (unsigned short*)(ws + 48234496);  // 2.10 MB [1024,1024]

  // 1) fused prepass: hs->bf16, transpose+convert both weight matrices
  prep<<<5120, 256, 0, stream>>>(hs, c_attn_w, c_proj_w, hsb, w1t, w2t);
  // 2) QKV GEMM -> qk (q pre-scaled by CF) + vt (V transposed)
  gemm_bf<0, 128><<<dim3(24, 32), 256, 0, stream>>>(hsb, w1t, c_attn_b, nullptr, qk, vt);
  // 3) attention -> aob bf16 (64 q-rows/wave)
  attn7<<<dim3(8, 16, 2), 256, 0, stream>>>(qk, vt, aob);
  // 4) output projection -> fp32 out (float4 stores)
  gemm_bf<2, 64><<<dim3(16, 32), 256, 0, stream>>>(aob, w2t, c_proj_b, out, nullptr, nullptr);
}

// Round 9
// 185.225 us; speedup vs baseline: 1.0659x; 1.0659x over previous
//
#include <hip/hip_runtime.h>

// B=2, S=2048, E=1024, H=16, D=64
#define SEQ 2048
#define EMB 1024
#define KDIM 1024
#define CF 0.180336880111113f  // (1/sqrt(64)) * log2(e), folded into Q

typedef __attribute__((ext_vector_type(8))) short short8_t;
typedef __attribute__((ext_vector_type(4))) float floatx4;
typedef __attribute__((ext_vector_type(4))) unsigned short ushort4_t;

#define GLOAD16(gp, lp)                                                        \
  __builtin_amdgcn_global_load_lds(                                            \
      (const __attribute__((address_space(1))) void*)(gp),                     \
      (__attribute__((address_space(3))) void*)(lp), 16, 0, 0)

#define WGBAR()                                   \
  do {                                            \
    __asm__ __volatile__("" ::: "memory");        \
    __builtin_amdgcn_s_barrier();                 \
    __asm__ __volatile__("" ::: "memory");        \
  } while (0)

static __device__ __forceinline__ unsigned short f2bf(float x) {
  unsigned int u = __float_as_uint(x);
  return (unsigned short)((u + 0x7fffu + ((u >> 16) & 1u)) >> 16);
}

// ---------------------------------------------------------------------------
// Fused prepass: blockIdx 0..4095   -> hs fp32 -> bf16
//                4096..4863         -> c_attn_w [1024,3072] -> w1t [3072,1024]
//                4864..5119         -> c_proj_w [1024,1024] -> w2t [1024,1024]
// ---------------------------------------------------------------------------
static __device__ __forceinline__ void tconv_tile(
    const float* __restrict__ W, unsigned short* __restrict__ T, int N, int K,
    int n0, int k0, int tid) {
  __shared__ float Tl[64][65];
  const int lx = tid & 15, ly = tid >> 4;
#pragma unroll
  for (int u = 0; u < 4; ++u) {
    int r = u * 16 + ly;
    float4 v = *(const float4*)&W[(size_t)(k0 + r) * N + n0 + lx * 4];
    Tl[r][lx * 4 + 0] = v.x;
    Tl[r][lx * 4 + 1] = v.y;
    Tl[r][lx * 4 + 2] = v.z;
    Tl[r][lx * 4 + 3] = v.w;
  }
  __syncthreads();
#pragma unroll
  for (int u = 0; u < 4; ++u) {
    int n = u * 16 + ly;
    ushort4_t h;
#pragma unroll
    for (int v = 0; v < 4; ++v) h[v] = f2bf(Tl[lx * 4 + v][n]);
    *(ushort4_t*)&T[(size_t)(n0 + n) * K + k0 + lx * 4] = h;
  }
}

__global__ __launch_bounds__(256) void prep(
    const float* __restrict__ hs, const float* __restrict__ caw,
    const float* __restrict__ cpw, unsigned short* __restrict__ hsb,
    unsigned short* __restrict__ w1t, unsigned short* __restrict__ w2t) {
  const int bid = blockIdx.x, tid = threadIdx.x;
  if (bid < 4096) {
    const int i = bid * 256 + tid;
    float4 v = *(const float4*)&hs[(size_t)i * 4];
    ushort4_t h = {f2bf(v.x), f2bf(v.y), f2bf(v.z), f2bf(v.w)};
    *(ushort4_t*)&hsb[(size_t)i * 4] = h;
  } else if (bid < 4864) {
    const int idx = bid - 4096;
    tconv_tile(caw, w1t, 3 * EMB, EMB, (idx % 48) * 64, (idx / 48) * 64, tid);
  } else {
    const int idx = bid - 4864;
    tconv_tile(cpw, w2t, EMB, EMB, (idx % 16) * 64, (idx / 16) * 64, tid);
  }
}

// ---------------------------------------------------------------------------
// Pipelined bf16 MFMA GEMM: BK=32, TRIPLE-buffered LDS, one s_barrier/iter,
// depth-2 DMA prefetch (attn6 pattern). Transposed-C accumulators.
// Tile 128 x BN.  A: [M,1024] bf16;  Bt: [N,1024] bf16 (W^T).
// XCD-aware block swizzle (%8 round-robin assumption) for L2 locality.
// MODE 0 (BN=128, 768 blocks): cols<2048 -> qk (q scaled CF); else vt.
// MODE 2 (BN=64, 512 blocks): fp32 out [M,1024].
// ---------------------------------------------------------------------------
template <int MODE, int BN>
__global__ __launch_bounds__(256) void gemm_pl(
    const unsigned short* __restrict__ Ag, const unsigned short* __restrict__ Bg,
    const float* __restrict__ bias, float* __restrict__ outF,
    unsigned short* __restrict__ qk, unsigned short* __restrict__ vt) {
  __shared__ __attribute__((aligned(16))) unsigned short Ah[3][128 * 32];
  __shared__ __attribute__((aligned(16))) unsigned short Bh[3][BN * 32];
  const int NJ = BN / 32;  // j-frag groups per wave

  const int tid = threadIdx.x;
  const int w = tid >> 6, lane = tid & 63;
  const int quad = lane >> 4, c = lane & 15;

  // XCD swizzle: rectangles per XCD sized to (mostly) fit the 4 MB L2
  int bm, bn;
  {
    const int L = blockIdx.x, x = L & 7, g = L >> 3;
    if (MODE == 0) {  // 768 blocks: per-XCD 16bm x 6bn (A 4MB + B 1.5MB)
      bm = ((x & 1) * 16 + (g & 15)) * 128;
      bn = ((x >> 1) * 6 + (g >> 4)) * 128;
    } else {  // 512 blocks: per-XCD 8bm x 8bn (A 2MB + B 1MB)
      bm = ((x & 3) * 8 + (g & 7)) * 128;
      bn = ((x >> 2) * 8 + (g >> 3)) * 64;
    }
  }
  const int wm = (w >> 1) * 64, wn = (w & 1) * (BN / 2);

  // staging: waves 0,1 -> A halves; waves 2,3 -> B halves (R4-verified idx)
  const unsigned short* gsrc = (w < 2) ? Ag : Bg;
  const int lbo = (w < 2) ? (w & 1) * 64 * 32 : (w & 1) * (BN / 2) * 32;
  const int rbase = (w < 2) ? (bm + (w & 1) * 64) : (bn + (w & 1) * (BN / 2));
  const int nloads = (w < 2) ? 4 : (BN / 32);
  const int srow = lane >> 2;                       // 0..15
  const int sblk = (lane & 3) ^ ((lane >> 3) & 3);  // XOR chunk swizzle
  const char* gp0 = (const char*)(gsrc + (size_t)(rbase + srow) * KDIM) + sblk * 16;

  floatx4 acc[4][NJ];
  const floatx4 z = {0.f, 0.f, 0.f, 0.f};
#pragma unroll
  for (int i = 0; i < 4; ++i)
#pragma unroll
    for (int j = 0; j < NJ; ++j) acc[i][j] = z;

  const int sw = (c >> 1) & 3;  // read-side swizzle key

#define STAGE_G(buf, kt)                                                       \
  do {                                                                         \
    unsigned short* ld = ((w < 2) ? Ah[buf] : Bh[buf]) + lbo;                  \
    const char* gp = gp0 + (size_t)(kt) * 64;                                  \
    for (int i_ = 0; i_ < nloads; ++i_)                                        \
      GLOAD16(gp + (size_t)i_ * 16 * (KDIM * 2), &ld[i_ * 512]);               \
  } while (0)

  STAGE_G(0, 0);
  STAGE_G(1, 1);

  for (int t = 0; t < 32; ++t) {
    // own stage-t landed (stage-(t+1) stays in flight)
    if (BN == 128 || w < 2) {
      __asm__ __volatile__("s_waitcnt vmcnt(4)" ::: "memory");
    } else {
      __asm__ __volatile__("s_waitcnt vmcnt(2)" ::: "memory");
    }
    WGBAR();  // all waves: stage-t landed AND compute t-1 finished
    STAGE_G((t + 2) % 3, (t + 2) & 31);  // overwrites buf read in iter t-1
    const unsigned short* Ac = Ah[t % 3];
    const unsigned short* Bc = Bh[t % 3];

    const int oct = (quad ^ sw) * 8;
    short8_t a[4], b[NJ];
#pragma unroll
    for (int i = 0; i < 4; ++i)
      a[i] = *(const short8_t*)&Ac[(wm + 16 * i + c) * 32 + oct];
#pragma unroll
    for (int j = 0; j < NJ; ++j)
      b[j] = *(const short8_t*)&Bc[(wn + 16 * j + c) * 32 + oct];
    // transposed: lane = A-row (m), regs = 4 consecutive B-rows (n)
#pragma unroll
    for (int i = 0; i < 4; ++i)
#pragma unroll
      for (int j = 0; j < NJ; ++j)
        acc[i][j] = __builtin_amdgcn_mfma_f32_16x16x32_bf16(b[j], a[i], acc[i][j], 0, 0, 0);
  }
#undef STAGE_G

  __asm__ __volatile__("s_waitcnt vmcnt(0)" ::: "memory");  // drain trailing DMA

#pragma unroll
  for (int i = 0; i < 4; ++i) {
    const int row = bm + wm + 16 * i + c;
#pragma unroll
    for (int j = 0; j < NJ; ++j) {
      const int col0 = bn + wn + 16 * j + quad * 4;
      floatx4 v = acc[i][j] + *(const floatx4*)&bias[col0];
      if (MODE == 0) {
        if (col0 < 1024) v = v * CF;
        if (col0 < 2048) {
          ushort4_t pk = {f2bf(v[0]), f2bf(v[1]), f2bf(v[2]), f2bf(v[3])};
          *(ushort4_t*)&qk[(size_t)row * 2048 + col0] = pk;
        } else {
          const int c2 = col0 - 2048, hh = c2 >> 6, d0 = c2 & 63;
          const int bb = row >> 11, s = row & 2047;
          unsigned short* vb = &vt[((size_t)(bb * 16 + hh) * 64 + d0) * 2048 + s];
          vb[0 * 2048] = f2bf(v[0]);
          vb[1 * 2048] = f2bf(v[1]);
          vb[2 * 2048] = f2bf(v[2]);
          vb[3 * 2048] = f2bf(v[3]);
        }
      } else {
        *(floatx4*)&outF[(size_t)row * 1024 + col0] = v;
      }
    }
  }
}

// ---------------------------------------------------------------------------
// K/V staging: waves 0,1 stage K rows w*32..+31; waves 2,3 stage V^T rows.
// ---------------------------------------------------------------------------
static __device__ __forceinline__ void stage_kv(
    int w, int srow, int sblkg, const unsigned short* __restrict__ gK,
    const unsigned short* __restrict__ gV, unsigned short* Kbuf,
    unsigned short* Vbuf, int jt) {
  if (w < 2) {
    const unsigned short* g0 = gK + (size_t)(jt * 64 + w * 32 + srow) * 2048 + sblkg * 8;
    unsigned short* l0 = &Kbuf[(w * 32) * 64];
#pragma unroll
    for (int i = 0; i < 4; ++i) GLOAD16(g0 + (size_t)i * 8 * 2048, &l0[i * 512]);
  } else {
    const unsigned short* g0 = gV + (size_t)((w - 2) * 32 + srow) * 2048 + jt * 64 + sblkg * 8;
    unsigned short* l0 = &Vbuf[((w - 2) * 32) * 64];
#pragma unroll
    for (int i = 0; i < 4; ++i) GLOAD16(g0 + (size_t)i * 8 * 2048, &l0[i * 512]);
  }
}

// ---------------------------------------------------------------------------
// bf16 MFMA flash attention (R7's attn6, proven 54.7 us): fixed-max softmax,
// S^T formulation, triple-buffered K/V, one barrier/tile, depth-2 prefetch.
// Grid (S/128, H, B), 256 thr. Wave w owns q-rows q0+32w..+31.
// ---------------------------------------------------------------------------
__global__ __launch_bounds__(256) void attn6(
    const unsigned short* __restrict__ qk, const unsigned short* __restrict__ vt,
    unsigned short* __restrict__ ao) {
  __shared__ __attribute__((aligned(16))) unsigned short Ks[3][64 * 64];  // 24 KB
  __shared__ __attribute__((aligned(16))) unsigned short Vs[3][64 * 64];  // 24 KB
  __shared__ __attribute__((aligned(16))) unsigned short Ps[4][32 * 64];  // 16 KB

  const int tid = threadIdx.x;
  const int w = tid >> 6, lane = tid & 63, quad = lane >> 4, c = lane & 15;
  const int q0 = blockIdx.x * 128, h = blockIdx.y, b = blockIdx.z;
  const int rk = c & 7;

  short8_t qf[2][2];
  {
    const size_t rb = (size_t)b * SEQ + q0 + w * 32;
#pragma unroll
    for (int mi = 0; mi < 2; ++mi) {
      const size_t qr = (rb + mi * 16 + c) * 2048 + h * 64 + quad * 8;
      qf[mi][0] = *(const short8_t*)&qk[qr];
      qf[mi][1] = *(const short8_t*)&qk[qr + 32];
    }
  }
  __asm__ __volatile__("s_waitcnt vmcnt(0)" ::: "memory");  // clean vmcnt queue

  floatx4 O[2][4], Osum[2];
  const floatx4 z = {0.f, 0.f, 0.f, 0.f};
#pragma unroll
  for (int mi = 0; mi < 2; ++mi) {
    Osum[mi] = z;
#pragma unroll
    for (int dg = 0; dg < 4; ++dg) O[mi][dg] = z;
  }
  short8_t ones;
#pragma unroll
  for (int e = 0; e < 8; ++e) ones[e] = (short)0x3F80;  // bf16 1.0

  const int srow = lane >> 3;           // 0..7
  const int sblkg = (lane & 7) ^ srow;  // staging chunk swizzle
  const unsigned short* gK = qk + (size_t)b * SEQ * 2048 + 1024 + h * 64;
  const unsigned short* gV = vt + (size_t)(b * 16 + h) * 64 * 2048;
  unsigned short* myPs = Ps[w];

  stage_kv(w, srow, sblkg, gK, gV, Ks[0], Vs[0], 0);
  stage_kv(w, srow, sblkg, gK, gV, Ks[1], Vs[1], 1);

  for (int t = 0; t < 32; ++t) {
    __asm__ __volatile__("s_waitcnt vmcnt(4)" ::: "memory");
    WGBAR();  // all waves: stage-t landed AND compute t-1 finished
    stage_kv(w, srow, sblkg, gK, gV, Ks[(t + 2) % 3], Vs[(t + 2) % 3], (t + 2) & 31);
    const unsigned short* Kc = Ks[t % 3];
    const unsigned short* Vc = Vs[t % 3];

    // S^T = K Q^T: lane = q, regs = j (consecutive within quad)
    floatx4 S[2][4];
#pragma unroll
    for (int mi = 0; mi < 2; ++mi)
#pragma unroll
      for (int jg = 0; jg < 4; ++jg) S[mi][jg] = z;
#pragma unroll
    for (int kd = 0; kd < 2; ++kd) {
      const int oct = ((4 * kd + quad) ^ rk) * 8;
#pragma unroll
      for (int jg = 0; jg < 4; ++jg) {
        short8_t kf = *(const short8_t*)&Kc[(jg * 16 + c) * 64 + oct];
#pragma unroll
        for (int mi = 0; mi < 2; ++mi)
          S[mi][jg] = __builtin_amdgcn_mfma_f32_16x16x32_bf16(kf, qf[mi][kd], S[mi][jg], 0, 0, 0);
      }
    }

    // P = exp2(S^T), truncate to bf16, pack consecutive-j pairs -> b32 LDS
#pragma unroll
    for (int mi = 0; mi < 2; ++mi) {
      const int qrow = (mi * 16 + c) * 64;
#pragma unroll
      for (int jg = 0; jg < 4; ++jg) {
        float p0 = __builtin_amdgcn_exp2f(S[mi][jg][0]);
        float p1 = __builtin_amdgcn_exp2f(S[mi][jg][1]);
        float p2 = __builtin_amdgcn_exp2f(S[mi][jg][2]);
        float p3 = __builtin_amdgcn_exp2f(S[mi][jg][3]);
        unsigned int pk01 = (__float_as_uint(p1) & 0xFFFF0000u) | (__float_as_uint(p0) >> 16);
        unsigned int pk23 = (__float_as_uint(p3) & 0xFFFF0000u) | (__float_as_uint(p2) >> 16);
        const int jp0 = 8 * jg + 2 * quad;
#pragma unroll
        for (int u = 0; u < 2; ++u) {
          const int jp = jp0 + u;
          const int off = ((jp >> 2) ^ rk) * 8 + (jp & 3) * 2;
          *(unsigned int*)&myPs[qrow + off] = u ? pk23 : pk01;
        }
      }
    }
    __asm__ __volatile__("s_waitcnt lgkmcnt(0)" ::: "memory");

    // PV: O^T += V^T P^T ; l += ones . P^T
#pragma unroll
    for (int kq = 0; kq < 2; ++kq) {
      const int oct = ((4 * kq + quad) ^ rk) * 8;
      short8_t pb[2];
#pragma unroll
      for (int mi = 0; mi < 2; ++mi) {
        pb[mi] = *(const short8_t*)&myPs[(mi * 16 + c) * 64 + oct];
        Osum[mi] = __builtin_amdgcn_mfma_f32_16x16x32_bf16(ones, pb[mi], Osum[mi], 0, 0, 0);
      }
#pragma unroll
      for (int dg = 0; dg < 4; ++dg) {
        short8_t vf = *(const short8_t*)&Vc[(dg * 16 + c) * 64 + oct];
#pragma unroll
        for (int mi = 0; mi < 2; ++mi)
          O[mi][dg] = __builtin_amdgcn_mfma_f32_16x16x32_bf16(vf, pb[mi], O[mi][dg], 0, 0, 0);
      }
    }
  }

  __asm__ __volatile__("s_waitcnt vmcnt(0)" ::: "memory");  // drain trailing DMA

  // epilogue: lane = q, regs = consecutive d -> packed ushort4 stores
#pragma unroll
  for (int mi = 0; mi < 2; ++mi) {
    const float inv = 1.0f / Osum[mi][0];
    const size_t row = (size_t)b * SEQ + q0 + w * 32 + mi * 16 + c;
#pragma unroll
    for (int dg = 0; dg < 4; ++dg) {
      ushort4_t ov = {f2bf(O[mi][dg][0] * inv), f2bf(O[mi][dg][1] * inv),
                      f2bf(O[mi][dg][2] * inv), f2bf(O[mi][dg][3] * inv)};
      *(ushort4_t*)&ao[row * EMB + h * 64 + dg * 16 + quad * 4] = ov;
    }
  }
}

// ---------------------------------------------------------------------------
extern "C" void kernel_launch(void* const* d_in, const int* in_sizes, int n_in,
                              void* d_out, int out_size, void* d_ws, size_t ws_size,
                              hipStream_t stream) {
  const float* hs = (const float*)d_in[0];        // [B,S,E]
  const float* c_attn_w = (const float*)d_in[1];  // [E,3E]
  const float* c_attn_b = (const float*)d_in[2];  // [3E]
  const float* c_proj_w = (const float*)d_in[3];  // [E,E]
  const float* c_proj_b = (const float*)d_in[4];  // [E]
  float* out = (float*)d_out;                     // [B,S,E] fp32

  char* ws = (char*)d_ws;
  unsigned short* hsb = (unsigned short*)(ws + 0);         // 8.39 MB [B,S,E] bf16
  unsigned short* qk  = (unsigned short*)(ws + 8388608);   // 16.8 MB [B,S,2048]
  unsigned short* vt  = (unsigned short*)(ws + 25165824);  // 8.39 MB [B,H,D,S]
  unsigned short* aob = (unsigned short*)(ws + 33554432);  // 8.39 MB [B,S,E] bf16
  unsigned short* w1t = (unsigned short*)(ws + 41943040);  // 6.29 MB [3072,1024]
  unsigned short* w2t = (unsigned short*)(ws + 48234496);  // 2.10 MB [1024,1024]

  // 1) fused prepass: hs->bf16, transpose+convert both weight matrices
  prep<<<5120, 256, 0, stream>>>(hs, c_attn_w, c_proj_w, hsb, w1t, w2t);
  // 2) QKV GEMM (pipelined, XCD-swizzled) -> qk (q pre-scaled by CF) + vt
  gemm_pl<0, 128><<<768, 256, 0, stream>>>(hsb, w1t, c_attn_b, nullptr, qk, vt);
  // 3) attention -> aob bf16 (proven attn6)
  attn6<<<dim3(16, 16, 2), 256, 0, stream>>>(qk, vt, aob);
  // 4) output projection (pipelined, XCD-swizzled) -> fp32 out
  gemm_pl<2, 64><<<512, 256, 0, stream>>>(aob, w2t, c_proj_b, out, nullptr, nullptr);
}